// Round 7
// baseline (248.512 us; speedup 1.0000x reference)
//
#include <hip/hip_runtime.h>
#include <math.h>

#define N_NODES 50000
#define N_EDGES 500000
#define DIM     128
#define NGRAPH  50
#define NPGC    1000
#define KSEL    500
#define SORT_N  1024
#define NBE     489    // ceil(N_EDGES / 1024)
#define NBN     49     // ceil(N_NODES / 1024)
#define GEMM_BLKS 391  // ceil(N_NODES / 128)
#define DEG_BLKS  1954 // ceil(N_EDGES / 256)
#define DOTS_BLKS 12500
#define NDINV     196  // ceil(N_NODES / 256)
#define GATH_BLKS 6250

// =============== K1: gemm (xw = x @ W_fu) || deg count ===============
// gemm blocks [0,391): 128 nodes x 128 ch, W-half + x-tile in 64KB LDS (XOR-swizzled),
// software-pipelined: half-1 global loads issued into regs before half-0 compute
// (3 barriers, prologue-only exposed latency). deg blocks: 1 edge/thread atomics.

__global__ __launch_bounds__(256) void k1_gemm_deg(const float* __restrict__ x,
                                                   const float* __restrict__ W,
                                                   float* __restrict__ xw,
                                                   const int* __restrict__ dst,
                                                   int* __restrict__ deg) {
    __shared__ float lds[16384];            // 64 KB
    int t = threadIdx.x;
    if (blockIdx.x >= GEMM_BLKS) {
        int e = (blockIdx.x - GEMM_BLKS) * 256 + t;
        if (e < N_EDGES) atomicAdd(&deg[dst[e]], 1);
        return;
    }
    float* Wt = lds;                        // [k][ch], 64*128
    float* Xt = lds + 64 * DIM;             // [node][k-half], swizzled, 128*64
    int cg = t & 15;
    int ng = t >> 4;
    int node_base = blockIdx.x * 128;

    float4 acc[8][2];
    #pragma unroll
    for (int nn = 0; nn < 8; nn++) {
        acc[nn][0] = make_float4(0.f, 0.f, 0.f, 0.f);
        acc[nn][1] = make_float4(0.f, 0.f, 0.f, 0.f);
    }

    int xrow  = t >> 4, xcol = t & 15;      // staging coords (row=f>>4 with f=t+i*256 keeps row=t>>4+16i)
    // ---- stage half 0 ----
    float4 w0[8], x0[8];
    {
        const float4* Wg = (const float4*)W;
        #pragma unroll
        for (int i = 0; i < 8; i++) w0[i] = Wg[t + i * 256];
        #pragma unroll
        for (int i = 0; i < 8; i++) {
            int node = node_base + xrow + i * 16;
            x0[i] = make_float4(0.f, 0.f, 0.f, 0.f);
            if (node < N_NODES) x0[i] = *(const float4*)&x[(size_t)node * DIM + xcol * 4];
        }
    }
    {
        float4* Wl = (float4*)Wt;
        #pragma unroll
        for (int i = 0; i < 8; i++) Wl[t + i * 256] = w0[i];
        #pragma unroll
        for (int i = 0; i < 8; i++) {
            int row = xrow + i * 16;
            *(float4*)&Xt[(row << 6) + ((xcol ^ (row & 15)) << 2)] = x0[i];
        }
    }
    __syncthreads();
    // ---- prefetch half 1 into regs (overlaps half-0 compute) ----
    float4 w1[8], x1[8];
    {
        const float4* Wg = (const float4*)(W + 64 * DIM);
        #pragma unroll
        for (int i = 0; i < 8; i++) w1[i] = Wg[t + i * 256];
        #pragma unroll
        for (int i = 0; i < 8; i++) {
            int node = node_base + xrow + i * 16;
            x1[i] = make_float4(0.f, 0.f, 0.f, 0.f);
            if (node < N_NODES) x1[i] = *(const float4*)&x[(size_t)node * DIM + 64 + xcol * 4];
        }
    }
    // ---- compute half 0 ----
    #pragma unroll 2
    for (int kc = 0; kc < 16; kc++) {
        int k = kc << 2;
        float4 wa[4], wb[4];
        #pragma unroll
        for (int kk = 0; kk < 4; kk++) {
            wa[kk] = *(const float4*)&Wt[(k + kk) * DIM + (cg << 2)];
            wb[kk] = *(const float4*)&Wt[(k + kk) * DIM + (cg << 2) + 64];
        }
        int csw = (kc ^ ng) << 2;
        #pragma unroll
        for (int nn = 0; nn < 8; nn++) {
            float4 xv = *(const float4*)&Xt[((ng + (nn << 4)) << 6) + csw];
            acc[nn][0].x += xv.x * wa[0].x + xv.y * wa[1].x + xv.z * wa[2].x + xv.w * wa[3].x;
            acc[nn][0].y += xv.x * wa[0].y + xv.y * wa[1].y + xv.z * wa[2].y + xv.w * wa[3].y;
            acc[nn][0].z += xv.x * wa[0].z + xv.y * wa[1].z + xv.z * wa[2].z + xv.w * wa[3].z;
            acc[nn][0].w += xv.x * wa[0].w + xv.y * wa[1].w + xv.z * wa[2].w + xv.w * wa[3].w;
            acc[nn][1].x += xv.x * wb[0].x + xv.y * wb[1].x + xv.z * wb[2].x + xv.w * wb[3].x;
            acc[nn][1].y += xv.x * wb[0].y + xv.y * wb[1].y + xv.z * wb[2].y + xv.w * wb[3].y;
            acc[nn][1].z += xv.x * wb[0].z + xv.y * wb[1].z + xv.z * wb[2].z + xv.w * wb[3].z;
            acc[nn][1].w += xv.x * wb[0].w + xv.y * wb[1].w + xv.z * wb[2].w + xv.w * wb[3].w;
        }
    }
    __syncthreads();
    // ---- write half 1 to LDS ----
    {
        float4* Wl = (float4*)Wt;
        #pragma unroll
        for (int i = 0; i < 8; i++) Wl[t + i * 256] = w1[i];
        #pragma unroll
        for (int i = 0; i < 8; i++) {
            int row = xrow + i * 16;
            *(float4*)&Xt[(row << 6) + ((xcol ^ (row & 15)) << 2)] = x1[i];
        }
    }
    __syncthreads();
    // ---- compute half 1 ----
    #pragma unroll 2
    for (int kc = 0; kc < 16; kc++) {
        int k = kc << 2;
        float4 wa[4], wb[4];
        #pragma unroll
        for (int kk = 0; kk < 4; kk++) {
            wa[kk] = *(const float4*)&Wt[(k + kk) * DIM + (cg << 2)];
            wb[kk] = *(const float4*)&Wt[(k + kk) * DIM + (cg << 2) + 64];
        }
        int csw = (kc ^ ng) << 2;
        #pragma unroll
        for (int nn = 0; nn < 8; nn++) {
            float4 xv = *(const float4*)&Xt[((ng + (nn << 4)) << 6) + csw];
            acc[nn][0].x += xv.x * wa[0].x + xv.y * wa[1].x + xv.z * wa[2].x + xv.w * wa[3].x;
            acc[nn][0].y += xv.x * wa[0].y + xv.y * wa[1].y + xv.z * wa[2].y + xv.w * wa[3].y;
            acc[nn][0].z += xv.x * wa[0].z + xv.y * wa[1].z + xv.z * wa[2].z + xv.w * wa[3].z;
            acc[nn][0].w += xv.x * wa[0].w + xv.y * wa[1].w + xv.z * wa[2].w + xv.w * wa[3].w;
            acc[nn][1].x += xv.x * wb[0].x + xv.y * wb[1].x + xv.z * wb[2].x + xv.w * wb[3].x;
            acc[nn][1].y += xv.x * wb[0].y + xv.y * wb[1].y + xv.z * wb[2].y + xv.w * wb[3].y;
            acc[nn][1].z += xv.x * wb[0].z + xv.y * wb[1].z + xv.z * wb[2].z + xv.w * wb[3].z;
            acc[nn][1].w += xv.x * wb[0].w + xv.y * wb[1].w + xv.z * wb[2].w + xv.w * wb[3].w;
        }
    }
    #pragma unroll
    for (int nn = 0; nn < 8; nn++) {
        int node = node_base + ng + (nn << 4);
        if (node < N_NODES) {
            *(float4*)&xw[(size_t)node * DIM + (cg << 2)]      = acc[nn][0];
            *(float4*)&xw[(size_t)node * DIM + (cg << 2) + 64] = acc[nn][1];
        }
    }
}

// =============== K2: dots || rowoff block-scan || dinv ===============

__global__ __launch_bounds__(256) void k2_dots_scan_dinv(const int* __restrict__ deg,
                                                         int* __restrict__ rowoff,
                                                         int* __restrict__ bsumsN,
                                                         const float* __restrict__ x,
                                                         const float* __restrict__ Ws,
                                                         const float* __restrict__ Wf,
                                                         const float* __restrict__ bf,
                                                         double* __restrict__ pack,
                                                         float* __restrict__ dinvf,
                                                         double* __restrict__ sf) {
    int t = threadIdx.x;
    int lane = t & 63, wid = t >> 6;
    int bid = blockIdx.x;
    if (bid < DOTS_BLKS) {
        int node = bid * 4 + wid;                // exactly 50000
        const float* xr = x + (size_t)node * DIM;
        double x1 = (double)xr[lane], x2 = (double)xr[lane + 64];
        double ps = x1 * (double)Ws[lane] + x2 * (double)Ws[lane + 64];
        double pf = x1 * (double)Wf[lane] + x2 * (double)Wf[lane + 64];
        for (int off = 32; off > 0; off >>= 1) {
            ps += __shfl_down(ps, off, 64);
            pf += __shfl_down(pf, off, 64);
        }
        if (lane == 0) {
            pack[2 * node + 1] = ps;             // xw_s
            sf[node] = pf + (double)bf[0];
        }
        return;
    }
    if (bid < DOTS_BLKS + NBN) {
        __shared__ int ws4[4];
        int base = (bid - DOTS_BLKS) * 1024 + t * 4;
        int v0 = (base + 0 < N_NODES) ? deg[base + 0] : 0;
        int v1 = (base + 1 < N_NODES) ? deg[base + 1] : 0;
        int v2 = (base + 2 < N_NODES) ? deg[base + 2] : 0;
        int v3 = (base + 3 < N_NODES) ? deg[base + 3] : 0;
        int s4 = v0 + v1 + v2 + v3;
        int incl = s4;
        #pragma unroll
        for (int off = 1; off < 64; off <<= 1) {
            int u = __shfl_up(incl, off, 64);
            if (lane >= off) incl += u;
        }
        if (lane == 63) ws4[wid] = incl;
        __syncthreads();
        int woff = 0;
        #pragma unroll
        for (int w = 0; w < 4; w++) if (w < wid) woff += ws4[w];
        int excl = incl - s4 + woff;
        if (base + 0 < N_NODES) rowoff[base + 0] = excl;
        if (base + 1 < N_NODES) rowoff[base + 1] = excl + v0;
        if (base + 2 < N_NODES) rowoff[base + 2] = excl + v0 + v1;
        if (base + 3 < N_NODES) rowoff[base + 3] = excl + v0 + v1 + v2;
        if (t == 255) bsumsN[bid - DOTS_BLKS] = woff + incl;
        return;
    }
    int i = (bid - DOTS_BLKS - NBN) * 256 + t;
    if (i < N_NODES) {
        double di = 1.0 / sqrt((double)(deg[i] + 1));
        pack[2 * i] = di;
        dinvf[i] = (float)di;
    }
}

// =============== K3: CSR fill (cursor atomics; payload = src id) ===============

__global__ __launch_bounds__(256) void k3_csr(const int* __restrict__ src,
                                              const int* __restrict__ dst,
                                              const int* __restrict__ rowoff,
                                              const int* __restrict__ bsumsN,
                                              int* __restrict__ cursor,
                                              int* __restrict__ csr) {
    __shared__ int bsN[64];
    int t = threadIdx.x;
    if (t < 64) {
        int v = (t < NBN) ? bsumsN[t] : 0;
        int incl = v;
        #pragma unroll
        for (int off = 1; off < 64; off <<= 1) {
            int u = __shfl_up(incl, off, 64);
            if (t >= off) incl += u;
        }
        bsN[t] = incl - v;
    }
    __syncthreads();
    int e = blockIdx.x * 256 + t;
    if (e >= N_EDGES) return;
    int d = dst[e];
    int pos = rowoff[d] + bsN[d >> 10] + atomicAdd(&cursor[d], 1);
    csr[pos] = src[e];
}

// =============== K4: per-graph score (CSR gather, f64) + top-k bitonic sort ===============
// 1024 threads: gather phase 1 node/thread; sort phase uses 512 compare threads.

__global__ __launch_bounds__(1024) void k4_topk(const int* __restrict__ csr,
                                                const int* __restrict__ rowoff,
                                                const int* __restrict__ bsumsN,
                                                const int* __restrict__ deg,
                                                const double* __restrict__ pack,
                                                const double* __restrict__ sf,
                                                const float* __restrict__ bs,
                                                int* __restrict__ perm, int* __restrict__ nodemap,
                                                float* __restrict__ scoref_sel,
                                                float* __restrict__ out, long o2, long o3) {
    __shared__ double key[SORT_N];
    __shared__ int    idx[SORT_N];
    __shared__ int    bsN[64];
    int g = blockIdx.x, t = threadIdx.x;
    if (t < 64) {
        int v = (t < NBN) ? bsumsN[t] : 0;
        int incl = v;
        #pragma unroll
        for (int off = 1; off < 64; off <<= 1) {
            int u = __shfl_up(incl, off, 64);
            if (t >= off) incl += u;
        }
        bsN[t] = incl - v;
    }
    __syncthreads();
    const double A = 0.6, OMA = 1.0 - 0.6;
    double bsv = (double)bs[0];
    {
        int i = t;
        if (i < NPGC) {
            int node = g * NPGC + i;
            int base = rowoff[node] + bsN[node >> 10];
            int cnt  = deg[node];
            double acc0 = 0.0, acc1 = 0.0;
            int e = 0;
            for (; e + 2 <= cnt; e += 2) {
                int s0 = csr[base + e];
                int s1 = csr[base + e + 1];
                double2 p0 = ((const double2*)pack)[s0];   // {dinv, xw_s}
                double2 p1 = ((const double2*)pack)[s1];
                acc0 += p0.x * p0.y;
                acc1 += p1.x * p1.y;
            }
            if (e < cnt) {
                int s0 = csr[base + e];
                double2 p0 = ((const double2*)pack)[s0];
                acc0 += p0.x * p0.y;
            }
            double2 pn = ((const double2*)pack)[node];
            double tot = pn.x * (acc0 + acc1) + pn.x * pn.x * pn.y + bsv;  // + self loop + b_s
            key[i] = tanh(A * tot + OMA * sf[node]);
            idx[i] = i;
        } else if (i < SORT_N) { key[i] = -1e300; idx[i] = i; }
    }
    __syncthreads();
    for (int size = 2; size <= SORT_N; size <<= 1) {
        for (int stride = size >> 1; stride > 0; stride >>= 1) {
            if (t < 512) {
                int a = ((t & ~(stride - 1)) << 1) | (t & (stride - 1));
                int b = a | stride;
                bool descFirst = ((a & size) == 0);
                double ka = key[a], kb = key[b];
                int ia = idx[a], ib = idx[b];
                bool aAfterB = (ka < kb) || (ka == kb && ia > ib);  // stable descending
                if (descFirst ? aAfterB : !aAfterB) {
                    key[a] = kb; key[b] = ka;
                    idx[a] = ib; idx[b] = ia;
                }
            }
            __syncthreads();
        }
    }
    if (t < KSEL) {
        int j = t;
        int node = g * NPGC + idx[j];
        int pos  = g * KSEL + j;
        perm[pos]        = node;
        nodemap[node]    = pos + 1;             // 0 = unselected
        scoref_sel[pos]  = (float)key[j];
        out[o2 + pos]    = (float)g;            // batch_out (== graph id)
        out[o3 + pos]    = (float)node;         // perm
    }
}

// =============== K5: edge flag+scan || fusion gather ===============

__global__ __launch_bounds__(256) void k5_escan_gather(const int* __restrict__ src,
                                                       const int* __restrict__ dst,
                                                       const int* __restrict__ nodemap,
                                                       int* __restrict__ epos,
                                                       int* __restrict__ bsumsE,
                                                       const float* __restrict__ xw,
                                                       const int* __restrict__ perm,
                                                       const int* __restrict__ rowoff,
                                                       const int* __restrict__ bsumsN,
                                                       const int* __restrict__ deg,
                                                       const int* __restrict__ csr,
                                                       const float* __restrict__ dinvf,
                                                       const float* __restrict__ scoref_sel,
                                                       const float* __restrict__ b_fu,
                                                       float* __restrict__ out, long o4) {
    int t = threadIdx.x;
    int lane = t & 63, wid = t >> 6;
    if (blockIdx.x < NBE) {
        __shared__ int ws4[4];
        int base = blockIdx.x * 1024 + t * 4;
        int v0 = 0, v1 = 0, v2 = 0, v3 = 0;
        if (base + 0 < N_EDGES) v0 = (nodemap[src[base + 0]] > 0 && nodemap[dst[base + 0]] > 0);
        if (base + 1 < N_EDGES) v1 = (nodemap[src[base + 1]] > 0 && nodemap[dst[base + 1]] > 0);
        if (base + 2 < N_EDGES) v2 = (nodemap[src[base + 2]] > 0 && nodemap[dst[base + 2]] > 0);
        if (base + 3 < N_EDGES) v3 = (nodemap[src[base + 3]] > 0 && nodemap[dst[base + 3]] > 0);
        int s4 = v0 + v1 + v2 + v3;
        int incl = s4;
        #pragma unroll
        for (int off = 1; off < 64; off <<= 1) {
            int u = __shfl_up(incl, off, 64);
            if (lane >= off) incl += u;
        }
        if (lane == 63) ws4[wid] = incl;
        __syncthreads();
        int woff = 0;
        #pragma unroll
        for (int w = 0; w < 4; w++) if (w < wid) woff += ws4[w];
        int excl = incl - s4 + woff;
        if (base + 0 < N_EDGES) epos[base + 0] = excl;
        if (base + 1 < N_EDGES) epos[base + 1] = excl + v0;
        if (base + 2 < N_EDGES) epos[base + 2] = excl + v0 + v1;
        if (base + 3 < N_EDGES) epos[base + 3] = excl + v0 + v1 + v2;
        if (t == 255) bsumsE[blockIdx.x] = woff + incl;
        return;
    }
    __shared__ int bsN[64];
    if (t < 64) {
        int v = (t < NBN) ? bsumsN[t] : 0;
        int incl = v;
        #pragma unroll
        for (int off = 1; off < 64; off <<= 1) {
            int u = __shfl_up(incl, off, 64);
            if (t >= off) incl += u;
        }
        bsN[t] = incl - v;
    }
    __syncthreads();
    int wave = (blockIdx.x - NBE) * 4 + wid;     // exactly 25000
    int p = perm[wave];
    float dpf = dinvf[p];
    int c2 = lane * 2;
    float2 v = ((const float2*)(xw + (size_t)p * DIM))[lane];
    float nself = dpf * dpf;
    float ax = nself * v.x, ay = nself * v.y;
    int beg = rowoff[p] + bsN[p >> 10], cnt = deg[p];
    int i = 0;
    for (; i + 2 <= cnt; i += 2) {
        int s0 = csr[beg + i];
        int s1 = csr[beg + i + 1];
        float2 u0 = ((const float2*)(xw + (size_t)s0 * DIM))[lane];
        float2 u1 = ((const float2*)(xw + (size_t)s1 * DIM))[lane];
        float n0 = dinvf[s0] * dpf, n1 = dinvf[s1] * dpf;
        ax += n0 * u0.x; ay += n0 * u0.y;
        ax += n1 * u1.x; ay += n1 * u1.y;
    }
    if (i < cnt) {
        int s0 = csr[beg + i];
        float2 u0 = ((const float2*)(xw + (size_t)s0 * DIM))[lane];
        float n0 = dinvf[s0] * dpf;
        ax += n0 * u0.x; ay += n0 * u0.y;
    }
    ax += b_fu[c2];
    ay += b_fu[c2 + 1];
    float sc = scoref_sel[wave];
    size_t ro = (size_t)wave * DIM + c2;
    out[o4 + ro]     = ax;        // x_ae
    out[o4 + ro + 1] = ay;
    out[ro]          = ax * sc;   // x_out
    out[ro + 1]      = ay * sc;
}

// =============== K6: edge compaction scatter (remap + write) ===============

__global__ __launch_bounds__(256) void k6_compact(const int* __restrict__ src,
                                                  const int* __restrict__ dst,
                                                  const int* __restrict__ nodemap,
                                                  const int* __restrict__ epos,
                                                  const int* __restrict__ bsumsE,
                                                  float* __restrict__ out_edges, long M) {
    __shared__ int bsE[512];
    int t = threadIdx.x;
    if (t < 64) {                               // wave 0: scan 489 entries, 8 chunks of 64
        int carry = 0;
        #pragma unroll
        for (int c = 0; c < 8; c++) {
            int i = c * 64 + t;
            int v = (i < NBE) ? bsumsE[i] : 0;
            int incl = v;
            #pragma unroll
            for (int off = 1; off < 64; off <<= 1) {
                int u = __shfl_up(incl, off, 64);
                if (t >= off) incl += u;
            }
            if (i < 512) bsE[i] = incl - v + carry;
            carry += __shfl(incl, 63, 64);
        }
    }
    __syncthreads();
    int e = blockIdx.x * 256 + t;
    if (e >= N_EDGES) return;
    int r = nodemap[src[e]], c = nodemap[dst[e]];
    if (r > 0 && c > 0) {
        int pos = epos[e] + bsE[e >> 10];
        out_edges[pos]     = (float)(r - 1);
        out_edges[M + pos] = (float)(c - 1);
    }
}

// ---------------- host ----------------

extern "C" void kernel_launch(void* const* d_in, const int* in_sizes, int n_in,
                              void* d_out, int out_size, void* d_ws, size_t ws_size,
                              hipStream_t stream) {
    const float* x    = (const float*)d_in[0];
    const int*   ei   = (const int*)d_in[1];
    const int*   src  = ei;
    const int*   dst  = ei + N_EDGES;
    const float* W_s  = (const float*)d_in[3];
    const float* b_s  = (const float*)d_in[4];
    const float* W_f  = (const float*)d_in[5];
    const float* b_f  = (const float*)d_in[6];
    const float* W_fu = (const float*)d_in[7];
    const float* b_fu = (const float*)d_in[8];
    float* out = (float*)d_out;

    char* wsp = (char*)d_ws;
    size_t off = 0;
    auto take = [&](size_t bytes) -> char* {
        char* p = wsp + off;
        off = (off + bytes + 255) & ~(size_t)255;
        return p;
    };
    // zero-cluster (single memset): deg | cursor | nodemap (0 = unselected)
    char*   zbase      = wsp;
    int*    deg        = (int*)   take((size_t)N_NODES * 4);
    int*    cursor     = (int*)   take((size_t)N_NODES * 4);
    int*    nodemap    = (int*)   take((size_t)N_NODES * 4);
    size_t  zbytes     = off;
    double* pack       = (double*)take((size_t)N_NODES * 16);  // {dinv, xw_s} per node
    double* sf         = (double*)take((size_t)N_NODES * 8);
    float*  dinvf      = (float*) take((size_t)N_NODES * 4);
    float*  scoref_sel = (float*) take((size_t)NGRAPH * KSEL * 4);
    int*    perm       = (int*)   take((size_t)NGRAPH * KSEL * 4);
    int*    rowoff     = (int*)   take((size_t)N_NODES * 4);
    int*    epos       = (int*)   take((size_t)N_EDGES * 4);
    int*    bsumsE     = (int*)   take((size_t)1024 * 4);
    int*    bsumsN     = (int*)   take((size_t)1024 * 4);
    int*    csr        = (int*)   take((size_t)N_EDGES * 4);
    float*  xw         = (float*) take((size_t)N_NODES * DIM * 4);

    // output layout: x_out[25000*128] | edge_index_new[2*M] | batch_out | perm | x_ae[25000*128]
    long M  = ((long)out_size - 6450000L) / 2;
    long o1 = 3200000L;
    long o2 = o1 + 2 * M;
    long o3 = o2 + (long)NGRAPH * KSEL;
    long o4 = o3 + (long)NGRAPH * KSEL;

    hipMemsetAsync(zbase, 0, zbytes, stream);

    k1_gemm_deg<<<GEMM_BLKS + DEG_BLKS, 256, 0, stream>>>(x, W_fu, xw, dst, deg);
    k2_dots_scan_dinv<<<DOTS_BLKS + NBN + NDINV, 256, 0, stream>>>(deg, rowoff, bsumsN,
                                                                   x, W_s, W_f, b_f,
                                                                   pack, dinvf, sf);
    k3_csr<<<DEG_BLKS, 256, 0, stream>>>(src, dst, rowoff, bsumsN, cursor, csr);
    k4_topk<<<NGRAPH, 1024, 0, stream>>>(csr, rowoff, bsumsN, deg, pack, sf, b_s,
                                         perm, nodemap, scoref_sel, out, o2, o3);
    k5_escan_gather<<<NBE + GATH_BLKS, 256, 0, stream>>>(src, dst, nodemap, epos, bsumsE,
                                                         xw, perm, rowoff, bsumsN, deg, csr,
                                                         dinvf, scoref_sel, b_fu, out, o4);
    k6_compact<<<DEG_BLKS, 256, 0, stream>>>(src, dst, nodemap, epos, bsumsE, out + o1, M);
}

// Round 8
// 240.242 us; speedup vs baseline: 1.0344x; 1.0344x over previous
//
#include <hip/hip_runtime.h>
#include <math.h>

#define N_NODES 50000
#define N_EDGES 500000
#define DIM     128
#define NGRAPH  50
#define NPGC    1000
#define KSEL    500
#define SORT_N  1024
#define NBE     489    // ceil(N_EDGES / 1024)
#define NBN     49     // ceil(N_NODES / 1024)
#define GEMM_BLKS 782  // ceil(N_NODES / 64)
#define DEG_BLKS  1954 // ceil(N_EDGES / 256)
#define DOTS_BLKS 12500
#define NDINV     196  // ceil(N_NODES / 256)
#define GATH_BLKS 6250

// =============== K1: gemm (xw = x @ W_fu) || deg count ===============
// gemm blocks [0,782): 64 nodes x 128 ch per block; W-half (32KB) + x-tile (16KB,
// XOR-swizzled) = 48KB LDS -> 3 blocks/CU (r6's 64KB tile gave only 2, and grid 391
// meant ~1.5 gemm blocks/CU -- nothing to overlap barrier drains with).
// NO register prefetch: r7's 140-VGPR version spilled 17MB to scratch.
// deg blocks: 1 edge/thread atomics.

__global__ __launch_bounds__(256) void k1_gemm_deg(const float* __restrict__ x,
                                                   const float* __restrict__ W,
                                                   float* __restrict__ xw,
                                                   const int* __restrict__ dst,
                                                   int* __restrict__ deg) {
    __shared__ float lds[12288];            // 48 KB
    int t = threadIdx.x;
    if (blockIdx.x >= GEMM_BLKS) {
        int e = (blockIdx.x - GEMM_BLKS) * 256 + t;
        if (e < N_EDGES) atomicAdd(&deg[dst[e]], 1);
        return;
    }
    float* Wt = lds;                        // [k][ch], 64*128 (32KB)
    float* Xt = lds + 64 * DIM;             // [node][k-half], swizzled, 64*64 (16KB)
    int cg = t & 15;
    int ng = t >> 4;
    int node_base = blockIdx.x * 64;

    float4 acc[4][2];
    #pragma unroll
    for (int nn = 0; nn < 4; nn++) {
        acc[nn][0] = make_float4(0.f, 0.f, 0.f, 0.f);
        acc[nn][1] = make_float4(0.f, 0.f, 0.f, 0.f);
    }
    for (int half = 0; half < 2; half++) {
        const float4* Wg = (const float4*)(W + half * 64 * DIM);
        float4* Wl = (float4*)Wt;
        #pragma unroll
        for (int i = 0; i < 8; i++) {
            int f = t + i * 256;                   // 0..2047
            Wl[f] = Wg[f];
        }
        #pragma unroll
        for (int i = 0; i < 4; i++) {
            int f = t + i * 256;                   // 0..1023
            int row = f >> 4, col = f & 15;
            int node = node_base + row;
            float4 v = make_float4(0.f, 0.f, 0.f, 0.f);
            if (node < N_NODES) v = *(const float4*)&x[(size_t)node * DIM + half * 64 + col * 4];
            *(float4*)&Xt[(row << 6) + ((col ^ (row & 15)) << 2)] = v;
        }
        __syncthreads();
        #pragma unroll 2
        for (int kc = 0; kc < 16; kc++) {
            int k = kc << 2;
            float4 wa[4], wb[4];
            #pragma unroll
            for (int kk = 0; kk < 4; kk++) {
                wa[kk] = *(const float4*)&Wt[(k + kk) * DIM + (cg << 2)];
                wb[kk] = *(const float4*)&Wt[(k + kk) * DIM + (cg << 2) + 64];
            }
            int csw = (kc ^ ng) << 2;              // row&15 == ng for all nn
            #pragma unroll
            for (int nn = 0; nn < 4; nn++) {
                float4 xv = *(const float4*)&Xt[((ng + (nn << 4)) << 6) + csw];
                acc[nn][0].x += xv.x * wa[0].x + xv.y * wa[1].x + xv.z * wa[2].x + xv.w * wa[3].x;
                acc[nn][0].y += xv.x * wa[0].y + xv.y * wa[1].y + xv.z * wa[2].y + xv.w * wa[3].y;
                acc[nn][0].z += xv.x * wa[0].z + xv.y * wa[1].z + xv.z * wa[2].z + xv.w * wa[3].z;
                acc[nn][0].w += xv.x * wa[0].w + xv.y * wa[1].w + xv.z * wa[2].w + xv.w * wa[3].w;
                acc[nn][1].x += xv.x * wb[0].x + xv.y * wb[1].x + xv.z * wb[2].x + xv.w * wb[3].x;
                acc[nn][1].y += xv.x * wb[0].y + xv.y * wb[1].y + xv.z * wb[2].y + xv.w * wb[3].y;
                acc[nn][1].z += xv.x * wb[0].z + xv.y * wb[1].z + xv.z * wb[2].z + xv.w * wb[3].z;
                acc[nn][1].w += xv.x * wb[0].w + xv.y * wb[1].w + xv.z * wb[2].w + xv.w * wb[3].w;
            }
        }
        __syncthreads();
    }
    #pragma unroll
    for (int nn = 0; nn < 4; nn++) {
        int node = node_base + ng + (nn << 4);
        if (node < N_NODES) {
            *(float4*)&xw[(size_t)node * DIM + (cg << 2)]      = acc[nn][0];
            *(float4*)&xw[(size_t)node * DIM + (cg << 2) + 64] = acc[nn][1];
        }
    }
}

// =============== K2: dots || rowoff block-scan || dinv ===============

__global__ __launch_bounds__(256) void k2_dots_scan_dinv(const int* __restrict__ deg,
                                                         int* __restrict__ rowoff,
                                                         int* __restrict__ bsumsN,
                                                         const float* __restrict__ x,
                                                         const float* __restrict__ Ws,
                                                         const float* __restrict__ Wf,
                                                         const float* __restrict__ bf,
                                                         double* __restrict__ pack,
                                                         float* __restrict__ dinvf,
                                                         double* __restrict__ sf) {
    int t = threadIdx.x;
    int lane = t & 63, wid = t >> 6;
    int bid = blockIdx.x;
    if (bid < DOTS_BLKS) {
        int node = bid * 4 + wid;                // exactly 50000
        const float* xr = x + (size_t)node * DIM;
        double x1 = (double)xr[lane], x2 = (double)xr[lane + 64];
        double ps = x1 * (double)Ws[lane] + x2 * (double)Ws[lane + 64];
        double pf = x1 * (double)Wf[lane] + x2 * (double)Wf[lane + 64];
        for (int off = 32; off > 0; off >>= 1) {
            ps += __shfl_down(ps, off, 64);
            pf += __shfl_down(pf, off, 64);
        }
        if (lane == 0) {
            pack[2 * node + 1] = ps;             // xw_s
            sf[node] = pf + (double)bf[0];
        }
        return;
    }
    if (bid < DOTS_BLKS + NBN) {
        __shared__ int ws4[4];
        int base = (bid - DOTS_BLKS) * 1024 + t * 4;
        int v0 = (base + 0 < N_NODES) ? deg[base + 0] : 0;
        int v1 = (base + 1 < N_NODES) ? deg[base + 1] : 0;
        int v2 = (base + 2 < N_NODES) ? deg[base + 2] : 0;
        int v3 = (base + 3 < N_NODES) ? deg[base + 3] : 0;
        int s4 = v0 + v1 + v2 + v3;
        int incl = s4;
        #pragma unroll
        for (int off = 1; off < 64; off <<= 1) {
            int u = __shfl_up(incl, off, 64);
            if (lane >= off) incl += u;
        }
        if (lane == 63) ws4[wid] = incl;
        __syncthreads();
        int woff = 0;
        #pragma unroll
        for (int w = 0; w < 4; w++) if (w < wid) woff += ws4[w];
        int excl = incl - s4 + woff;
        if (base + 0 < N_NODES) rowoff[base + 0] = excl;
        if (base + 1 < N_NODES) rowoff[base + 1] = excl + v0;
        if (base + 2 < N_NODES) rowoff[base + 2] = excl + v0 + v1;
        if (base + 3 < N_NODES) rowoff[base + 3] = excl + v0 + v1 + v2;
        if (t == 255) bsumsN[bid - DOTS_BLKS] = woff + incl;
        return;
    }
    int i = (bid - DOTS_BLKS - NBN) * 256 + t;
    if (i < N_NODES) {
        double di = 1.0 / sqrt((double)(deg[i] + 1));
        pack[2 * i] = di;
        dinvf[i] = (float)di;
    }
}

// =============== K3: CSR fill (cursor atomics; payload = src id) ===============

__global__ __launch_bounds__(256) void k3_csr(const int* __restrict__ src,
                                              const int* __restrict__ dst,
                                              const int* __restrict__ rowoff,
                                              const int* __restrict__ bsumsN,
                                              int* __restrict__ cursor,
                                              int* __restrict__ csr) {
    __shared__ int bsN[64];
    int t = threadIdx.x;
    if (t < 64) {
        int v = (t < NBN) ? bsumsN[t] : 0;
        int incl = v;
        #pragma unroll
        for (int off = 1; off < 64; off <<= 1) {
            int u = __shfl_up(incl, off, 64);
            if (t >= off) incl += u;
        }
        bsN[t] = incl - v;
    }
    __syncthreads();
    int e = blockIdx.x * 256 + t;
    if (e >= N_EDGES) return;
    int d = dst[e];
    int pos = rowoff[d] + bsN[d >> 10] + atomicAdd(&cursor[d], 1);
    csr[pos] = src[e];
}

// =============== K4: per-graph score (CSR gather, f64) + top-k bitonic sort ===============

__global__ __launch_bounds__(1024) void k4_topk(const int* __restrict__ csr,
                                                const int* __restrict__ rowoff,
                                                const int* __restrict__ bsumsN,
                                                const int* __restrict__ deg,
                                                const double* __restrict__ pack,
                                                const double* __restrict__ sf,
                                                const float* __restrict__ bs,
                                                int* __restrict__ perm, int* __restrict__ nodemap,
                                                float* __restrict__ scoref_sel,
                                                float* __restrict__ out, long o2, long o3) {
    __shared__ double key[SORT_N];
    __shared__ int    idx[SORT_N];
    __shared__ int    bsN[64];
    int g = blockIdx.x, t = threadIdx.x;
    if (t < 64) {
        int v = (t < NBN) ? bsumsN[t] : 0;
        int incl = v;
        #pragma unroll
        for (int off = 1; off < 64; off <<= 1) {
            int u = __shfl_up(incl, off, 64);
            if (t >= off) incl += u;
        }
        bsN[t] = incl - v;
    }
    __syncthreads();
    const double A = 0.6, OMA = 1.0 - 0.6;
    double bsv = (double)bs[0];
    {
        int i = t;
        if (i < NPGC) {
            int node = g * NPGC + i;
            int base = rowoff[node] + bsN[node >> 10];
            int cnt  = deg[node];
            double acc0 = 0.0, acc1 = 0.0;
            int e = 0;
            for (; e + 2 <= cnt; e += 2) {
                int s0 = csr[base + e];
                int s1 = csr[base + e + 1];
                double2 p0 = ((const double2*)pack)[s0];   // {dinv, xw_s}
                double2 p1 = ((const double2*)pack)[s1];
                acc0 += p0.x * p0.y;
                acc1 += p1.x * p1.y;
            }
            if (e < cnt) {
                int s0 = csr[base + e];
                double2 p0 = ((const double2*)pack)[s0];
                acc0 += p0.x * p0.y;
            }
            double2 pn = ((const double2*)pack)[node];
            double tot = pn.x * (acc0 + acc1) + pn.x * pn.x * pn.y + bsv;  // + self loop + b_s
            key[i] = tanh(A * tot + OMA * sf[node]);
            idx[i] = i;
        } else if (i < SORT_N) { key[i] = -1e300; idx[i] = i; }
    }
    __syncthreads();
    for (int size = 2; size <= SORT_N; size <<= 1) {
        for (int stride = size >> 1; stride > 0; stride >>= 1) {
            if (t < 512) {
                int a = ((t & ~(stride - 1)) << 1) | (t & (stride - 1));
                int b = a | stride;
                bool descFirst = ((a & size) == 0);
                double ka = key[a], kb = key[b];
                int ia = idx[a], ib = idx[b];
                bool aAfterB = (ka < kb) || (ka == kb && ia > ib);  // stable descending
                if (descFirst ? aAfterB : !aAfterB) {
                    key[a] = kb; key[b] = ka;
                    idx[a] = ib; idx[b] = ia;
                }
            }
            __syncthreads();
        }
    }
    if (t < KSEL) {
        int j = t;
        int node = g * NPGC + idx[j];
        int pos  = g * KSEL + j;
        perm[pos]        = node;
        nodemap[node]    = pos + 1;             // 0 = unselected
        scoref_sel[pos]  = (float)key[j];
        out[o2 + pos]    = (float)g;            // batch_out (== graph id)
        out[o3 + pos]    = (float)node;         // perm
    }
}

// =============== K5: edge flag+scan || fusion gather ===============

__global__ __launch_bounds__(256) void k5_escan_gather(const int* __restrict__ src,
                                                       const int* __restrict__ dst,
                                                       const int* __restrict__ nodemap,
                                                       int* __restrict__ epos,
                                                       int* __restrict__ bsumsE,
                                                       const float* __restrict__ xw,
                                                       const int* __restrict__ perm,
                                                       const int* __restrict__ rowoff,
                                                       const int* __restrict__ bsumsN,
                                                       const int* __restrict__ deg,
                                                       const int* __restrict__ csr,
                                                       const float* __restrict__ dinvf,
                                                       const float* __restrict__ scoref_sel,
                                                       const float* __restrict__ b_fu,
                                                       float* __restrict__ out, long o4) {
    int t = threadIdx.x;
    int lane = t & 63, wid = t >> 6;
    if (blockIdx.x < NBE) {
        __shared__ int ws4[4];
        int base = blockIdx.x * 1024 + t * 4;
        int v0 = 0, v1 = 0, v2 = 0, v3 = 0;
        if (base + 0 < N_EDGES) v0 = (nodemap[src[base + 0]] > 0 && nodemap[dst[base + 0]] > 0);
        if (base + 1 < N_EDGES) v1 = (nodemap[src[base + 1]] > 0 && nodemap[dst[base + 1]] > 0);
        if (base + 2 < N_EDGES) v2 = (nodemap[src[base + 2]] > 0 && nodemap[dst[base + 2]] > 0);
        if (base + 3 < N_EDGES) v3 = (nodemap[src[base + 3]] > 0 && nodemap[dst[base + 3]] > 0);
        int s4 = v0 + v1 + v2 + v3;
        int incl = s4;
        #pragma unroll
        for (int off = 1; off < 64; off <<= 1) {
            int u = __shfl_up(incl, off, 64);
            if (lane >= off) incl += u;
        }
        if (lane == 63) ws4[wid] = incl;
        __syncthreads();
        int woff = 0;
        #pragma unroll
        for (int w = 0; w < 4; w++) if (w < wid) woff += ws4[w];
        int excl = incl - s4 + woff;
        if (base + 0 < N_EDGES) epos[base + 0] = excl;
        if (base + 1 < N_EDGES) epos[base + 1] = excl + v0;
        if (base + 2 < N_EDGES) epos[base + 2] = excl + v0 + v1;
        if (base + 3 < N_EDGES) epos[base + 3] = excl + v0 + v1 + v2;
        if (t == 255) bsumsE[blockIdx.x] = woff + incl;
        return;
    }
    __shared__ int bsN[64];
    if (t < 64) {
        int v = (t < NBN) ? bsumsN[t] : 0;
        int incl = v;
        #pragma unroll
        for (int off = 1; off < 64; off <<= 1) {
            int u = __shfl_up(incl, off, 64);
            if (t >= off) incl += u;
        }
        bsN[t] = incl - v;
    }
    __syncthreads();
    int wave = (blockIdx.x - NBE) * 4 + wid;     // exactly 25000
    int p = perm[wave];
    float dpf = dinvf[p];
    int c2 = lane * 2;
    float2 v = ((const float2*)(xw + (size_t)p * DIM))[lane];
    float nself = dpf * dpf;
    float ax = nself * v.x, ay = nself * v.y;
    int beg = rowoff[p] + bsN[p >> 10], cnt = deg[p];
    int i = 0;
    for (; i + 2 <= cnt; i += 2) {
        int s0 = csr[beg + i];
        int s1 = csr[beg + i + 1];
        float2 u0 = ((const float2*)(xw + (size_t)s0 * DIM))[lane];
        float2 u1 = ((const float2*)(xw + (size_t)s1 * DIM))[lane];
        float n0 = dinvf[s0] * dpf, n1 = dinvf[s1] * dpf;
        ax += n0 * u0.x; ay += n0 * u0.y;
        ax += n1 * u1.x; ay += n1 * u1.y;
    }
    if (i < cnt) {
        int s0 = csr[beg + i];
        float2 u0 = ((const float2*)(xw + (size_t)s0 * DIM))[lane];
        float n0 = dinvf[s0] * dpf;
        ax += n0 * u0.x; ay += n0 * u0.y;
    }
    ax += b_fu[c2];
    ay += b_fu[c2 + 1];
    float sc = scoref_sel[wave];
    size_t ro = (size_t)wave * DIM + c2;
    out[o4 + ro]     = ax;        // x_ae
    out[o4 + ro + 1] = ay;
    out[ro]          = ax * sc;   // x_out
    out[ro + 1]      = ay * sc;
}

// =============== K6: edge compaction scatter (remap + write) ===============

__global__ __launch_bounds__(256) void k6_compact(const int* __restrict__ src,
                                                  const int* __restrict__ dst,
                                                  const int* __restrict__ nodemap,
                                                  const int* __restrict__ epos,
                                                  const int* __restrict__ bsumsE,
                                                  float* __restrict__ out_edges, long M) {
    __shared__ int bsE[512];
    int t = threadIdx.x;
    if (t < 64) {                               // wave 0: scan 489 entries, 8 chunks of 64
        int carry = 0;
        #pragma unroll
        for (int c = 0; c < 8; c++) {
            int i = c * 64 + t;
            int v = (i < NBE) ? bsumsE[i] : 0;
            int incl = v;
            #pragma unroll
            for (int off = 1; off < 64; off <<= 1) {
                int u = __shfl_up(incl, off, 64);
                if (t >= off) incl += u;
            }
            if (i < 512) bsE[i] = incl - v + carry;
            carry += __shfl(incl, 63, 64);
        }
    }
    __syncthreads();
    int e = blockIdx.x * 256 + t;
    if (e >= N_EDGES) return;
    int r = nodemap[src[e]], c = nodemap[dst[e]];
    if (r > 0 && c > 0) {
        int pos = epos[e] + bsE[e >> 10];
        out_edges[pos]     = (float)(r - 1);
        out_edges[M + pos] = (float)(c - 1);
    }
}

// ---------------- host ----------------

extern "C" void kernel_launch(void* const* d_in, const int* in_sizes, int n_in,
                              void* d_out, int out_size, void* d_ws, size_t ws_size,
                              hipStream_t stream) {
    const float* x    = (const float*)d_in[0];
    const int*   ei   = (const int*)d_in[1];
    const int*   src  = ei;
    const int*   dst  = ei + N_EDGES;
    const float* W_s  = (const float*)d_in[3];
    const float* b_s  = (const float*)d_in[4];
    const float* W_f  = (const float*)d_in[5];
    const float* b_f  = (const float*)d_in[6];
    const float* W_fu = (const float*)d_in[7];
    const float* b_fu = (const float*)d_in[8];
    float* out = (float*)d_out;

    char* wsp = (char*)d_ws;
    size_t off = 0;
    auto take = [&](size_t bytes) -> char* {
        char* p = wsp + off;
        off = (off + bytes + 255) & ~(size_t)255;
        return p;
    };
    // zero-cluster (single memset): deg | cursor | nodemap (0 = unselected)
    char*   zbase      = wsp;
    int*    deg        = (int*)   take((size_t)N_NODES * 4);
    int*    cursor     = (int*)   take((size_t)N_NODES * 4);
    int*    nodemap    = (int*)   take((size_t)N_NODES * 4);
    size_t  zbytes     = off;
    double* pack       = (double*)take((size_t)N_NODES * 16);  // {dinv, xw_s} per node
    double* sf         = (double*)take((size_t)N_NODES * 8);
    float*  dinvf      = (float*) take((size_t)N_NODES * 4);
    float*  scoref_sel = (float*) take((size_t)NGRAPH * KSEL * 4);
    int*    perm       = (int*)   take((size_t)NGRAPH * KSEL * 4);
    int*    rowoff     = (int*)   take((size_t)N_NODES * 4);
    int*    epos       = (int*)   take((size_t)N_EDGES * 4);
    int*    bsumsE     = (int*)   take((size_t)1024 * 4);
    int*    bsumsN     = (int*)   take((size_t)1024 * 4);
    int*    csr        = (int*)   take((size_t)N_EDGES * 4);
    float*  xw         = (float*) take((size_t)N_NODES * DIM * 4);

    // output layout: x_out[25000*128] | edge_index_new[2*M] | batch_out | perm | x_ae[25000*128]
    long M  = ((long)out_size - 6450000L) / 2;
    long o1 = 3200000L;
    long o2 = o1 + 2 * M;
    long o3 = o2 + (long)NGRAPH * KSEL;
    long o4 = o3 + (long)NGRAPH * KSEL;

    hipMemsetAsync(zbase, 0, zbytes, stream);

    k1_gemm_deg<<<GEMM_BLKS + DEG_BLKS, 256, 0, stream>>>(x, W_fu, xw, dst, deg);
    k2_dots_scan_dinv<<<DOTS_BLKS + NBN + NDINV, 256, 0, stream>>>(deg, rowoff, bsumsN,
                                                                   x, W_s, W_f, b_f,
                                                                   pack, dinvf, sf);
    k3_csr<<<DEG_BLKS, 256, 0, stream>>>(src, dst, rowoff, bsumsN, cursor, csr);
    k4_topk<<<NGRAPH, 1024, 0, stream>>>(csr, rowoff, bsumsN, deg, pack, sf, b_s,
                                         perm, nodemap, scoref_sel, out, o2, o3);
    k5_escan_gather<<<NBE + GATH_BLKS, 256, 0, stream>>>(src, dst, nodemap, epos, bsumsE,
                                                         xw, perm, rowoff, bsumsN, deg, csr,
                                                         dinvf, scoref_sel, b_fu, out, o4);
    k6_compact<<<DEG_BLKS, 256, 0, stream>>>(src, dst, nodemap, epos, bsumsE, out + o1, M);
}

// Round 9
// 232.988 us; speedup vs baseline: 1.0666x; 1.0311x over previous
//
#include <hip/hip_runtime.h>
#include <math.h>

#define N_NODES 50000
#define N_EDGES 500000
#define DIM     128
#define NGRAPH  50
#define NPGC    1000
#define KSEL    500
#define SORT_N  1024
#define NBE     489    // ceil(N_EDGES / 1024)
#define NBN     49     // ceil(N_NODES / 1024)
#define GEMM_BLKS 782  // ceil(N_NODES / 64)
#define DEG_BLKS  1954 // ceil(N_EDGES / 256)
#define DOTS_BLKS 12500
#define NDINV     196  // ceil(N_NODES / 256)
#define GATH_BLKS 6250

typedef short s16x8 __attribute__((ext_vector_type(8)));  // 8 bf16 (4 VGPRs)
typedef float f32x4 __attribute__((ext_vector_type(4)));  // MFMA acc

// float -> bf16(hi) + bf16(lo of residual), round-to-nearest-even
__device__ __forceinline__ void f2bf2(float v, unsigned short& h, unsigned short& l) {
    unsigned u = __float_as_uint(v);
    unsigned hb = (u + 0x7FFFu + ((u >> 16) & 1u)) >> 16;
    h = (unsigned short)hb;
    float r = v - __uint_as_float(hb << 16);
    unsigned u2 = __float_as_uint(r);
    l = (unsigned short)((u2 + 0x7FFFu + ((u2 >> 16) & 1u)) >> 16);
}

// =============== K0: W_fu -> transposed, k-block-swizzled bf16 hi/lo ===============
// Wt[h][ch][64k], element (h,ch,kl) at ch*64 + ((kl>>3)^(ch&7))*8 + (kl&7).
// Pre-applying transpose+swizzle here makes k1's W staging pure b128 copies.

__global__ __launch_bounds__(256) void k0_wprep(const float* __restrict__ W,
                                                unsigned short* __restrict__ Wth,
                                                unsigned short* __restrict__ Wtl) {
    int idx = blockIdx.x * 256 + threadIdx.x;    // grid 64 -> exactly 16384
    int k = idx >> 7, ch = idx & 127;
    unsigned short h, l;
    f2bf2(W[idx], h, l);
    int hh = k >> 6, kl = k & 63;
    int pos = hh * 8192 + ch * 64 + ((((kl >> 3) ^ (ch & 7))) << 3) + (kl & 7);
    Wth[pos] = h;
    Wtl[pos] = l;
}

// =============== K1: MFMA gemm (xw = x @ W_fu, bf16x3 split) || deg count ===============
// gemm blocks [0,782): 64 nodes x 128 ch. Per wave: 16 nodes x 128 ch via
// mfma_f32_16x16x32_bf16; acc = hi*hi + hi*lo + lo*hi (err ~1e-4, threshold ~4% of max).
// LDS 48KB: x hi/lo (2x8KB, XOR-swizzled k-blocks) + W^T hi/lo (2x16KB, pre-swizzled).
// A-frag: lane m=lane&15 (node), k=quad*8+j. B-frag: n=lane&15 (ch), k=quad*8+j.
// C/D: col(ch)=lane&15, row(node)=quad*4+reg  [guide-verified layouts].
// deg blocks [782,...): 1 edge/thread atomics.

__global__ __launch_bounds__(256) void k1_gemm_deg(const float* __restrict__ x,
                                                   const unsigned short* __restrict__ Wth,
                                                   const unsigned short* __restrict__ Wtl,
                                                   float* __restrict__ xw,
                                                   const int* __restrict__ dst,
                                                   int* __restrict__ deg) {
    __shared__ unsigned short lds_sh[24576];     // 48 KB
    int t = threadIdx.x;
    if (blockIdx.x >= GEMM_BLKS) {
        int e = (blockIdx.x - GEMM_BLKS) * 256 + t;
        if (e < N_EDGES) atomicAdd(&deg[dst[e]], 1);
        return;
    }
    unsigned short* XH = lds_sh;                 // 64 x 64 bf16
    unsigned short* XL = lds_sh + 4096;
    unsigned short* WH = lds_sh + 8192;          // 128 x 64 bf16 (transposed W)
    unsigned short* WL = lds_sh + 16384;
    const int wv = t >> 6, lane = t & 63;
    const int q = lane >> 4, mm = lane & 15;
    int node_base = blockIdx.x * 64;

    f32x4 zero4v = {0.f, 0.f, 0.f, 0.f};
    f32x4 acc[8];
    #pragma unroll
    for (int ct = 0; ct < 8; ct++) acc[ct] = zero4v;

    for (int h = 0; h < 2; h++) {
        { // W^T halves: linear b128 copies (pre-swizzled in k0)
            const s16x8* GH = (const s16x8*)(Wth + h * 8192);
            const s16x8* GL = (const s16x8*)(Wtl + h * 8192);
            s16x8* LH = (s16x8*)WH;
            s16x8* LL = (s16x8*)WL;
            #pragma unroll
            for (int i = 0; i < 4; i++) {
                LH[t + i * 256] = GH[t + i * 256];
                LL[t + i * 256] = GL[t + i * 256];
            }
        }
        // x half: global fp32 -> bf16 hi/lo, swizzled k-blocks
        #pragma unroll
        for (int i = 0; i < 4; i++) {
            int f = t + i * 256;                 // 0..1023
            int r = f >> 4, c4 = f & 15;
            int node = node_base + r;
            float4 v = make_float4(0.f, 0.f, 0.f, 0.f);
            if (node < N_NODES) v = *(const float4*)&x[(size_t)node * DIM + h * 64 + c4 * 4];
            unsigned short h0, l0, h1, l1, h2, l2, h3, l3;
            f2bf2(v.x, h0, l0); f2bf2(v.y, h1, l1);
            f2bf2(v.z, h2, l2); f2bf2(v.w, h3, l3);
            int off = r * 64 + ((((c4 >> 1) ^ (r & 7))) << 3) + ((c4 & 1) << 2);
            *(uint2*)&XH[off] = make_uint2((unsigned)h0 | ((unsigned)h1 << 16),
                                           (unsigned)h2 | ((unsigned)h3 << 16));
            *(uint2*)&XL[off] = make_uint2((unsigned)l0 | ((unsigned)l1 << 16),
                                           (unsigned)l2 | ((unsigned)l3 << 16));
        }
        __syncthreads();
        #pragma unroll
        for (int c = 0; c < 2; c++) {            // two K=32 chunks per half
            int jb = c * 4 + q;                  // k-block 0..7
            int aoff = (wv * 16 + mm) * 64 + ((jb ^ (mm & 7)) << 3);
            s16x8 ah = *(const s16x8*)&XH[aoff];
            s16x8 al = *(const s16x8*)&XL[aoff];
            #pragma unroll
            for (int ct = 0; ct < 8; ct++) {
                int ch = ct * 16 + mm;
                int boff = ch * 64 + ((jb ^ (ch & 7)) << 3);
                s16x8 bh = *(const s16x8*)&WH[boff];
                s16x8 bl = *(const s16x8*)&WL[boff];
                acc[ct] = __builtin_amdgcn_mfma_f32_16x16x32_bf16(ah, bh, acc[ct], 0, 0, 0);
                acc[ct] = __builtin_amdgcn_mfma_f32_16x16x32_bf16(ah, bl, acc[ct], 0, 0, 0);
                acc[ct] = __builtin_amdgcn_mfma_f32_16x16x32_bf16(al, bh, acc[ct], 0, 0, 0);
            }
        }
        __syncthreads();
    }
    #pragma unroll
    for (int ct = 0; ct < 8; ct++) {
        #pragma unroll
        for (int r = 0; r < 4; r++) {
            int node = node_base + wv * 16 + q * 4 + r;
            if (node < N_NODES) xw[(size_t)node * DIM + ct * 16 + mm] = acc[ct][r];
        }
    }
}

// =============== K2: dots || rowoff block-scan || dinv ===============

__global__ __launch_bounds__(256) void k2_dots_scan_dinv(const int* __restrict__ deg,
                                                         int* __restrict__ rowoff,
                                                         int* __restrict__ bsumsN,
                                                         const float* __restrict__ x,
                                                         const float* __restrict__ Ws,
                                                         const float* __restrict__ Wf,
                                                         const float* __restrict__ bf,
                                                         double* __restrict__ pack,
                                                         float* __restrict__ dinvf,
                                                         double* __restrict__ sf) {
    int t = threadIdx.x;
    int lane = t & 63, wid = t >> 6;
    int bid = blockIdx.x;
    if (bid < DOTS_BLKS) {
        int node = bid * 4 + wid;                // exactly 50000
        const float* xr = x + (size_t)node * DIM;
        double x1 = (double)xr[lane], x2 = (double)xr[lane + 64];
        double ps = x1 * (double)Ws[lane] + x2 * (double)Ws[lane + 64];
        double pf = x1 * (double)Wf[lane] + x2 * (double)Wf[lane + 64];
        for (int off = 32; off > 0; off >>= 1) {
            ps += __shfl_down(ps, off, 64);
            pf += __shfl_down(pf, off, 64);
        }
        if (lane == 0) {
            pack[2 * node + 1] = ps;             // xw_s
            sf[node] = pf + (double)bf[0];
        }
        return;
    }
    if (bid < DOTS_BLKS + NBN) {
        __shared__ int ws4[4];
        int base = (bid - DOTS_BLKS) * 1024 + t * 4;
        int v0 = (base + 0 < N_NODES) ? deg[base + 0] : 0;
        int v1 = (base + 1 < N_NODES) ? deg[base + 1] : 0;
        int v2 = (base + 2 < N_NODES) ? deg[base + 2] : 0;
        int v3 = (base + 3 < N_NODES) ? deg[base + 3] : 0;
        int s4 = v0 + v1 + v2 + v3;
        int incl = s4;
        #pragma unroll
        for (int off = 1; off < 64; off <<= 1) {
            int u = __shfl_up(incl, off, 64);
            if (lane >= off) incl += u;
        }
        if (lane == 63) ws4[wid] = incl;
        __syncthreads();
        int woff = 0;
        #pragma unroll
        for (int w = 0; w < 4; w++) if (w < wid) woff += ws4[w];
        int excl = incl - s4 + woff;
        if (base + 0 < N_NODES) rowoff[base + 0] = excl;
        if (base + 1 < N_NODES) rowoff[base + 1] = excl + v0;
        if (base + 2 < N_NODES) rowoff[base + 2] = excl + v0 + v1;
        if (base + 3 < N_NODES) rowoff[base + 3] = excl + v0 + v1 + v2;
        if (t == 255) bsumsN[bid - DOTS_BLKS] = woff + incl;
        return;
    }
    int i = (bid - DOTS_BLKS - NBN) * 256 + t;
    if (i < N_NODES) {
        double di = 1.0 / sqrt((double)(deg[i] + 1));
        pack[2 * i] = di;
        dinvf[i] = (float)di;
    }
}

// =============== K3: CSR fill (cursor atomics; payload = src id) ===============

__global__ __launch_bounds__(256) void k3_csr(const int* __restrict__ src,
                                              const int* __restrict__ dst,
                                              const int* __restrict__ rowoff,
                                              const int* __restrict__ bsumsN,
                                              int* __restrict__ cursor,
                                              int* __restrict__ csr) {
    __shared__ int bsN[64];
    int t = threadIdx.x;
    if (t < 64) {
        int v = (t < NBN) ? bsumsN[t] : 0;
        int incl = v;
        #pragma unroll
        for (int off = 1; off < 64; off <<= 1) {
            int u = __shfl_up(incl, off, 64);
            if (t >= off) incl += u;
        }
        bsN[t] = incl - v;
    }
    __syncthreads();
    int e = blockIdx.x * 256 + t;
    if (e >= N_EDGES) return;
    int d = dst[e];
    int pos = rowoff[d] + bsN[d >> 10] + atomicAdd(&cursor[d], 1);
    csr[pos] = src[e];
}

// =============== K4: per-graph score (CSR gather, f64) + top-k bitonic sort ===============

__global__ __launch_bounds__(1024) void k4_topk(const int* __restrict__ csr,
                                                const int* __restrict__ rowoff,
                                                const int* __restrict__ bsumsN,
                                                const int* __restrict__ deg,
                                                const double* __restrict__ pack,
                                                const double* __restrict__ sf,
                                                const float* __restrict__ bs,
                                                int* __restrict__ perm, int* __restrict__ nodemap,
                                                float* __restrict__ scoref_sel,
                                                float* __restrict__ out, long o2, long o3) {
    __shared__ double key[SORT_N];
    __shared__ int    idx[SORT_N];
    __shared__ int    bsN[64];
    int g = blockIdx.x, t = threadIdx.x;
    if (t < 64) {
        int v = (t < NBN) ? bsumsN[t] : 0;
        int incl = v;
        #pragma unroll
        for (int off = 1; off < 64; off <<= 1) {
            int u = __shfl_up(incl, off, 64);
            if (t >= off) incl += u;
        }
        bsN[t] = incl - v;
    }
    __syncthreads();
    const double A = 0.6, OMA = 1.0 - 0.6;
    double bsv = (double)bs[0];
    {
        int i = t;
        if (i < NPGC) {
            int node = g * NPGC + i;
            int base = rowoff[node] + bsN[node >> 10];
            int cnt  = deg[node];
            double acc0 = 0.0, acc1 = 0.0;
            int e = 0;
            for (; e + 2 <= cnt; e += 2) {
                int s0 = csr[base + e];
                int s1 = csr[base + e + 1];
                double2 p0 = ((const double2*)pack)[s0];   // {dinv, xw_s}
                double2 p1 = ((const double2*)pack)[s1];
                acc0 += p0.x * p0.y;
                acc1 += p1.x * p1.y;
            }
            if (e < cnt) {
                int s0 = csr[base + e];
                double2 p0 = ((const double2*)pack)[s0];
                acc0 += p0.x * p0.y;
            }
            double2 pn = ((const double2*)pack)[node];
            double tot = pn.x * (acc0 + acc1) + pn.x * pn.x * pn.y + bsv;  // + self loop + b_s
            key[i] = tanh(A * tot + OMA * sf[node]);
            idx[i] = i;
        } else if (i < SORT_N) { key[i] = -1e300; idx[i] = i; }
    }
    __syncthreads();
    for (int size = 2; size <= SORT_N; size <<= 1) {
        for (int stride = size >> 1; stride > 0; stride >>= 1) {
            if (t < 512) {
                int a = ((t & ~(stride - 1)) << 1) | (t & (stride - 1));
                int b = a | stride;
                bool descFirst = ((a & size) == 0);
                double ka = key[a], kb = key[b];
                int ia = idx[a], ib = idx[b];
                bool aAfterB = (ka < kb) || (ka == kb && ia > ib);  // stable descending
                if (descFirst ? aAfterB : !aAfterB) {
                    key[a] = kb; key[b] = ka;
                    idx[a] = ib; idx[b] = ia;
                }
            }
            __syncthreads();
        }
    }
    if (t < KSEL) {
        int j = t;
        int node = g * NPGC + idx[j];
        int pos  = g * KSEL + j;
        perm[pos]        = node;
        nodemap[node]    = pos + 1;             // 0 = unselected
        scoref_sel[pos]  = (float)key[j];
        out[o2 + pos]    = (float)g;            // batch_out (== graph id)
        out[o3 + pos]    = (float)node;         // perm
    }
}

// =============== K5: edge flag+scan || fusion gather ===============

__global__ __launch_bounds__(256) void k5_escan_gather(const int* __restrict__ src,
                                                       const int* __restrict__ dst,
                                                       const int* __restrict__ nodemap,
                                                       int* __restrict__ epos,
                                                       int* __restrict__ bsumsE,
                                                       const float* __restrict__ xw,
                                                       const int* __restrict__ perm,
                                                       const int* __restrict__ rowoff,
                                                       const int* __restrict__ bsumsN,
                                                       const int* __restrict__ deg,
                                                       const int* __restrict__ csr,
                                                       const float* __restrict__ dinvf,
                                                       const float* __restrict__ scoref_sel,
                                                       const float* __restrict__ b_fu,
                                                       float* __restrict__ out, long o4) {
    int t = threadIdx.x;
    int lane = t & 63, wid = t >> 6;
    if (blockIdx.x < NBE) {
        __shared__ int ws4[4];
        int base = blockIdx.x * 1024 + t * 4;
        int v0 = 0, v1 = 0, v2 = 0, v3 = 0;
        if (base + 0 < N_EDGES) v0 = (nodemap[src[base + 0]] > 0 && nodemap[dst[base + 0]] > 0);
        if (base + 1 < N_EDGES) v1 = (nodemap[src[base + 1]] > 0 && nodemap[dst[base + 1]] > 0);
        if (base + 2 < N_EDGES) v2 = (nodemap[src[base + 2]] > 0 && nodemap[dst[base + 2]] > 0);
        if (base + 3 < N_EDGES) v3 = (nodemap[src[base + 3]] > 0 && nodemap[dst[base + 3]] > 0);
        int s4 = v0 + v1 + v2 + v3;
        int incl = s4;
        #pragma unroll
        for (int off = 1; off < 64; off <<= 1) {
            int u = __shfl_up(incl, off, 64);
            if (lane >= off) incl += u;
        }
        if (lane == 63) ws4[wid] = incl;
        __syncthreads();
        int woff = 0;
        #pragma unroll
        for (int w = 0; w < 4; w++) if (w < wid) woff += ws4[w];
        int excl = incl - s4 + woff;
        if (base + 0 < N_EDGES) epos[base + 0] = excl;
        if (base + 1 < N_EDGES) epos[base + 1] = excl + v0;
        if (base + 2 < N_EDGES) epos[base + 2] = excl + v0 + v1;
        if (base + 3 < N_EDGES) epos[base + 3] = excl + v0 + v1 + v2;
        if (t == 255) bsumsE[blockIdx.x] = woff + incl;
        return;
    }
    __shared__ int bsN[64];
    if (t < 64) {
        int v = (t < NBN) ? bsumsN[t] : 0;
        int incl = v;
        #pragma unroll
        for (int off = 1; off < 64; off <<= 1) {
            int u = __shfl_up(incl, off, 64);
            if (t >= off) incl += u;
        }
        bsN[t] = incl - v;
    }
    __syncthreads();
    int wave = (blockIdx.x - NBE) * 4 + wid;     // exactly 25000
    int p = perm[wave];
    float dpf = dinvf[p];
    int c2 = lane * 2;
    float2 v = ((const float2*)(xw + (size_t)p * DIM))[lane];
    float nself = dpf * dpf;
    float ax = nself * v.x, ay = nself * v.y;
    int beg = rowoff[p] + bsN[p >> 10], cnt = deg[p];
    int i = 0;
    for (; i + 2 <= cnt; i += 2) {
        int s0 = csr[beg + i];
        int s1 = csr[beg + i + 1];
        float2 u0 = ((const float2*)(xw + (size_t)s0 * DIM))[lane];
        float2 u1 = ((const float2*)(xw + (size_t)s1 * DIM))[lane];
        float n0 = dinvf[s0] * dpf, n1 = dinvf[s1] * dpf;
        ax += n0 * u0.x; ay += n0 * u0.y;
        ax += n1 * u1.x; ay += n1 * u1.y;
    }
    if (i < cnt) {
        int s0 = csr[beg + i];
        float2 u0 = ((const float2*)(xw + (size_t)s0 * DIM))[lane];
        float n0 = dinvf[s0] * dpf;
        ax += n0 * u0.x; ay += n0 * u0.y;
    }
    ax += b_fu[c2];
    ay += b_fu[c2 + 1];
    float sc = scoref_sel[wave];
    size_t ro = (size_t)wave * DIM + c2;
    out[o4 + ro]     = ax;        // x_ae
    out[o4 + ro + 1] = ay;
    out[ro]          = ax * sc;   // x_out
    out[ro + 1]      = ay * sc;
}

// =============== K6: edge compaction scatter (remap + write) ===============

__global__ __launch_bounds__(256) void k6_compact(const int* __restrict__ src,
                                                  const int* __restrict__ dst,
                                                  const int* __restrict__ nodemap,
                                                  const int* __restrict__ epos,
                                                  const int* __restrict__ bsumsE,
                                                  float* __restrict__ out_edges, long M) {
    __shared__ int bsE[512];
    int t = threadIdx.x;
    if (t < 64) {                               // wave 0: scan 489 entries, 8 chunks of 64
        int carry = 0;
        #pragma unroll
        for (int c = 0; c < 8; c++) {
            int i = c * 64 + t;
            int v = (i < NBE) ? bsumsE[i] : 0;
            int incl = v;
            #pragma unroll
            for (int off = 1; off < 64; off <<= 1) {
                int u = __shfl_up(incl, off, 64);
                if (t >= off) incl += u;
            }
            if (i < 512) bsE[i] = incl - v + carry;
            carry += __shfl(incl, 63, 64);
        }
    }
    __syncthreads();
    int e = blockIdx.x * 256 + t;
    if (e >= N_EDGES) return;
    int r = nodemap[src[e]], c = nodemap[dst[e]];
    if (r > 0 && c > 0) {
        int pos = epos[e] + bsE[e >> 10];
        out_edges[pos]     = (float)(r - 1);
        out_edges[M + pos] = (float)(c - 1);
    }
}

// ---------------- host ----------------

extern "C" void kernel_launch(void* const* d_in, const int* in_sizes, int n_in,
                              void* d_out, int out_size, void* d_ws, size_t ws_size,
                              hipStream_t stream) {
    const float* x    = (const float*)d_in[0];
    const int*   ei   = (const int*)d_in[1];
    const int*   src  = ei;
    const int*   dst  = ei + N_EDGES;
    const float* W_s  = (const float*)d_in[3];
    const float* b_s  = (const float*)d_in[4];
    const float* W_f  = (const float*)d_in[5];
    const float* b_f  = (const float*)d_in[6];
    const float* W_fu = (const float*)d_in[7];
    const float* b_fu = (const float*)d_in[8];
    float* out = (float*)d_out;

    char* wsp = (char*)d_ws;
    size_t off = 0;
    auto take = [&](size_t bytes) -> char* {
        char* p = wsp + off;
        off = (off + bytes + 255) & ~(size_t)255;
        return p;
    };
    // zero-cluster (single memset): deg | cursor | nodemap (0 = unselected)
    char*   zbase      = wsp;
    int*    deg        = (int*)   take((size_t)N_NODES * 4);
    int*    cursor     = (int*)   take((size_t)N_NODES * 4);
    int*    nodemap    = (int*)   take((size_t)N_NODES * 4);
    size_t  zbytes     = off;
    double* pack       = (double*)take((size_t)N_NODES * 16);  // {dinv, xw_s} per node
    double* sf         = (double*)take((size_t)N_NODES * 8);
    float*  dinvf      = (float*) take((size_t)N_NODES * 4);
    float*  scoref_sel = (float*) take((size_t)NGRAPH * KSEL * 4);
    int*    perm       = (int*)   take((size_t)NGRAPH * KSEL * 4);
    int*    rowoff     = (int*)   take((size_t)N_NODES * 4);
    int*    epos       = (int*)   take((size_t)N_EDGES * 4);
    int*    bsumsE     = (int*)   take((size_t)1024 * 4);
    int*    bsumsN     = (int*)   take((size_t)1024 * 4);
    int*    csr        = (int*)   take((size_t)N_EDGES * 4);
    float*  xw         = (float*) take((size_t)N_NODES * DIM * 4);
    unsigned short* Wth = (unsigned short*)take((size_t)16384 * 2);  // W^T bf16 hi, swizzled
    unsigned short* Wtl = (unsigned short*)take((size_t)16384 * 2);  // W^T bf16 lo

    // output layout: x_out[25000*128] | edge_index_new[2*M] | batch_out | perm | x_ae[25000*128]
    long M  = ((long)out_size - 6450000L) / 2;
    long o1 = 3200000L;
    long o2 = o1 + 2 * M;
    long o3 = o2 + (long)NGRAPH * KSEL;
    long o4 = o3 + (long)NGRAPH * KSEL;

    hipMemsetAsync(zbase, 0, zbytes, stream);

    k0_wprep<<<64, 256, 0, stream>>>(W_fu, Wth, Wtl);
    k1_gemm_deg<<<GEMM_BLKS + DEG_BLKS, 256, 0, stream>>>(x, Wth, Wtl, xw, dst, deg);
    k2_dots_scan_dinv<<<DOTS_BLKS + NBN + NDINV, 256, 0, stream>>>(deg, rowoff, bsumsN,
                                                                   x, W_s, W_f, b_f,
                                                                   pack, dinvf, sf);
    k3_csr<<<DEG_BLKS, 256, 0, stream>>>(src, dst, rowoff, bsumsN, cursor, csr);
    k4_topk<<<NGRAPH, 1024, 0, stream>>>(csr, rowoff, bsumsN, deg, pack, sf, b_s,
                                         perm, nodemap, scoref_sel, out, o2, o3);
    k5_escan_gather<<<NBE + GATH_BLKS, 256, 0, stream>>>(src, dst, nodemap, epos, bsumsE,
                                                         xw, perm, rowoff, bsumsN, deg, csr,
                                                         dinvf, scoref_sel, b_fu, out, o4);
    k6_compact<<<DEG_BLKS, 256, 0, stream>>>(src, dst, nodemap, epos, bsumsE, out + o1, M);
}